// Round 1
// baseline (282.203 us; speedup 1.0000x reference)
//
#include <hip/hip_runtime.h>

typedef unsigned short u16;
typedef unsigned int   u32;

using bf16x8 = __attribute__((ext_vector_type(8))) short;
using f32x4  = __attribute__((ext_vector_type(4))) float;

#define MFMA16(a, b, c) __builtin_amdgcn_mfma_f32_16x16x32_bf16((a), (b), (c), 0, 0, 0)

__device__ __forceinline__ u16 f2bf(float f) {
  union { float f; u32 u; } x; x.f = f;
  u32 r = x.u + 0x7fffu + ((x.u >> 16) & 1u);
  return (u16)(r >> 16);
}

// async global->LDS, 16B per lane; LDS dest must be wave-uniform base (HW adds lane*16)
__device__ __forceinline__ void gl2lds16(const void* g, void* l) {
  __builtin_amdgcn_global_load_lds(
      (const __attribute__((address_space(1))) u32*)g,
      (__attribute__((address_space(3))) u32*)l, 16, 0, 0);
}

// ---------------- fp32 -> bf16 elementwise (8 elems/thread) ----------------
__global__ __launch_bounds__(256) void cvt_f32_bf16(const float* __restrict__ in,
                                                    u16* __restrict__ out, long n8) {
  long i = (long)blockIdx.x * 256 + threadIdx.x;
  if (i >= n8) return;
  const float4* p = (const float4*)(in + i * 8);
  float4 a = p[0], b = p[1];
  u16 t[8] __attribute__((aligned(16)));
  t[0] = f2bf(a.x); t[1] = f2bf(a.y); t[2] = f2bf(a.z); t[3] = f2bf(a.w);
  t[4] = f2bf(b.x); t[5] = f2bf(b.y); t[6] = f2bf(b.z); t[7] = f2bf(b.w);
  *(uint4*)(out + i * 8) = *(uint4*)t;
}

// ---------------- weight convert + transpose: W[K][N] f32 -> Wt[N][K] bf16 --
__global__ __launch_bounds__(256) void wt_cvt_t(const float* __restrict__ W,
                                                u16* __restrict__ Wt, int K, int N) {
  __shared__ u16 t[64][66];
  int tilesN = N >> 6;
  int k0 = ((int)blockIdx.x / tilesN) << 6;
  int n0 = ((int)blockIdx.x % tilesN) << 6;
  int tid = threadIdx.x;
  int c4 = (tid & 15) * 4, r16 = tid >> 4;
#pragma unroll
  for (int p = 0; p < 4; ++p) {
    int row = r16 + p * 16;
    float4 f = *(const float4*)(W + (size_t)(k0 + row) * N + n0 + c4);
    t[row][c4 + 0] = f2bf(f.x);
    t[row][c4 + 1] = f2bf(f.y);
    t[row][c4 + 2] = f2bf(f.z);
    t[row][c4 + 3] = f2bf(f.w);
  }
  __syncthreads();
  int c8 = (tid & 7) * 8, r32 = tid >> 3;
#pragma unroll
  for (int p = 0; p < 2; ++p) {
    int n = r32 + p * 32;
    u16 tmp[8] __attribute__((aligned(16)));
#pragma unroll
    for (int e = 0; e < 8; ++e) tmp[e] = t[c8 + e][n];
    *(uint4*)(Wt + (size_t)(n0 + n) * K + k0 + c8) = *(uint4*)tmp;
  }
}

// ---------------- bf16 batched transpose: vs[BH][512][64] -> vsT[BH][64][512]
__global__ __launch_bounds__(256) void vs_transpose(const u16* __restrict__ vs,
                                                    u16* __restrict__ vsT) {
  __shared__ u16 t[64][66];
  int bh = blockIdx.x >> 3, lt = blockIdx.x & 7;
  int tid = threadIdx.x;
  int c8 = (tid & 7) * 8, r32 = tid >> 3;
  const u16* src = vs + (size_t)bh * 32768 + (size_t)lt * 4096;
#pragma unroll
  for (int p = 0; p < 2; ++p) {
    int row = r32 + p * 32;
    uint4 d = *(const uint4*)(src + (size_t)row * 64 + c8);
    u16 tmp[8] __attribute__((aligned(16)));
    *(uint4*)tmp = d;
#pragma unroll
    for (int e = 0; e < 8; ++e) t[row][c8 + e] = tmp[e];
  }
  __syncthreads();
  u16* dst = vsT + (size_t)bh * 32768 + lt * 64;
#pragma unroll
  for (int p = 0; p < 2; ++p) {
    int dv = r32 + p * 32;
    u16 tmp[8] __attribute__((aligned(16)));
#pragma unroll
    for (int e = 0; e < 8; ++e) tmp[e] = t[c8 + e][dv];
    *(uint4*)(dst + (size_t)dv * 512 + c8) = *(uint4*)tmp;
  }
}

// ---------------- MFMA GEMM: C[M][N] = A[M][K] * Bt[N][K]^T + bias ---------
// 128x128 tile, BK=64, 4 waves (2x2), 64x64 per wave, XOR-swizzled LDS.
// MODE 0: relu, write bf16 out + f32 out (v-proj)
// MODE 1: relu, write bf16 out (s-proj)
// MODE 2: write bf16 permuted to [B][H][L][64] (q / vs proj)
// MODE 3: out = acc + bias + add0[m][n] + add1[m&511][n], f32 (out-proj + residual + pos)
template <int MODE>
__global__ __launch_bounds__(256) void gemm_bf16(
    const u16* __restrict__ A, const u16* __restrict__ Bt,
    const float* __restrict__ bias, u16* __restrict__ outb, float* __restrict__ outf,
    const float* __restrict__ add0, const float* __restrict__ add1,
    int M, int N, int K) {
  __shared__ u16 sA[128 * 64];
  __shared__ u16 sB[128 * 64];
  int tilesN = N >> 7;
  int tm = (int)blockIdx.x / tilesN, tn = (int)blockIdx.x % tilesN;
  int m0 = tm << 7, n0 = tn << 7;
  int tid = threadIdx.x, w = tid >> 6, l = tid & 63;
  int wm = (w >> 1) << 6, wn = (w & 1) << 6;
  int c16 = l & 15, g16 = (l >> 4) * 16;  // byte offset of lane's k-group

  f32x4 acc[4][4];
#pragma unroll
  for (int i = 0; i < 4; ++i)
#pragma unroll
    for (int j = 0; j < 4; ++j) acc[i][j] = (f32x4){0.f, 0.f, 0.f, 0.f};

  int nk = K >> 6;
  for (int kt = 0; kt < nk; ++kt) {
    __syncthreads();
    const u16* Ab = A + (size_t)m0 * K + kt * 64;
    const u16* Bb = Bt + (size_t)n0 * K + kt * 64;
#pragma unroll
    for (int j = 0; j < 4; ++j) {
      int chunk = w * 4 + j;            // 16 chunks of 1024B per 16KB tile
      int lin = chunk * 1024 + l * 16;  // linear LDS byte this lane fills
      int row = lin >> 7;               // tile row (128B rows)
      int cb = (lin & 127) ^ ((row & 7) << 4);  // pre-swizzled source column
      gl2lds16(Ab + (size_t)row * K + (cb >> 1), (char*)sA + chunk * 1024);
      gl2lds16(Bb + (size_t)row * K + (cb >> 1), (char*)sB + chunk * 1024);
    }
    __syncthreads();
#pragma unroll
    for (int kk = 0; kk < 2; ++kk) {
      bf16x8 af[4], bfr[4];
#pragma unroll
      for (int i = 0; i < 4; ++i) {
        int ar = wm + i * 16 + c16;
        af[i] = *(const bf16x8*)((const char*)sA + ar * 128 +
                                 ((kk * 64 + g16) ^ ((ar & 7) << 4)));
        int br = wn + i * 16 + c16;
        bfr[i] = *(const bf16x8*)((const char*)sB + br * 128 +
                                  ((kk * 64 + g16) ^ ((br & 7) << 4)));
      }
#pragma unroll
      for (int i = 0; i < 4; ++i)
#pragma unroll
        for (int j = 0; j < 4; ++j) acc[i][j] = MFMA16(af[i], bfr[j], acc[i][j]);
    }
  }
#pragma unroll
  for (int i = 0; i < 4; ++i) {
#pragma unroll
    for (int j = 0; j < 4; ++j) {
#pragma unroll
      for (int r = 0; r < 4; ++r) {
        int gm = m0 + wm + i * 16 + (l >> 4) * 4 + r;
        int gn = n0 + wn + j * 16 + c16;
        float v = acc[i][j][r] + bias[gn];
        if (MODE == 0) {
          v = fmaxf(v, 0.f);
          outb[(size_t)gm * N + gn] = f2bf(v);
          outf[(size_t)gm * N + gn] = v;
        } else if (MODE == 1) {
          v = fmaxf(v, 0.f);
          outb[(size_t)gm * N + gn] = f2bf(v);
        } else if (MODE == 2) {
          int hh = gn >> 6, dk = gn & 63, bb2 = gm >> 9, ll2 = gm & 511;
          outb[(((size_t)bb2 * 16 + hh) * 512 + ll2) * 64 + dk] = f2bf(v);
        } else {
          v += add0[(size_t)gm * N + gn] + add1[(size_t)(gm & 511) * N + gn];
          outf[(size_t)gm * N + gn] = v;
        }
      }
    }
  }
}

// ---------------- fused attention (flash-style, per (b,h,qtile)) -----------
// q[BH][512][64], kv[BH][512][64], kvT[BH][64][512] all bf16; ctx[B*512][1024] bf16
__global__ __launch_bounds__(256) void attn_kernel(const u16* __restrict__ q,
                                                   const u16* __restrict__ kv,
                                                   const u16* __restrict__ kvT,
                                                   u16* __restrict__ ctx) {
  __shared__ u16 sQ[64 * 64];
  __shared__ u16 sK[64 * 64];
  __shared__ u16 sVT[64 * 64];
  __shared__ u16 sP[4][16 * 64];

  int bh = blockIdx.x >> 3, qt = blockIdx.x & 7;
  int b = bh >> 4, h = bh & 15;
  int tid = threadIdx.x, w = tid >> 6, l = tid & 63;
  int c16 = l & 15, g16 = (l >> 4) * 16;

  // stage Q tile (64x64) once, pre-swizzled source
  const u16* qbase = q + (size_t)bh * 32768 + (size_t)qt * 4096;
#pragma unroll
  for (int j = 0; j < 2; ++j) {
    int chunk = w * 2 + j;
    int lin = chunk * 1024 + l * 16;
    int row = lin >> 7;
    int cb = (lin & 127) ^ ((row & 7) << 4);
    gl2lds16(qbase + (size_t)row * 64 + (cb >> 1), (char*)sQ + chunk * 1024);
  }

  bf16x8 aq[2];
  f32x4 of[4];
#pragma unroll
  for (int n = 0; n < 4; ++n) of[n] = (f32x4){0.f, 0.f, 0.f, 0.f};
  float m_run[4] = {-1e30f, -1e30f, -1e30f, -1e30f};
  float l_run[4] = {0.f, 0.f, 0.f, 0.f};

  for (int c = 0; c < 8; ++c) {
    __syncthreads();  // previous chunk's compute done before overwrite
    const u16* kbase = kv + (size_t)bh * 32768 + (size_t)c * 4096;
    const u16* vtbase = kvT + (size_t)bh * 32768 + c * 64;
#pragma unroll
    for (int j = 0; j < 2; ++j) {
      int chunk = w * 2 + j;
      int lin = chunk * 1024 + l * 16;
      int row = lin >> 7;
      int cb = (lin & 127) ^ ((row & 7) << 4);
      gl2lds16(kbase + (size_t)row * 64 + (cb >> 1), (char*)sK + chunk * 1024);
      gl2lds16(vtbase + (size_t)row * 512 + (cb >> 1), (char*)sVT + chunk * 1024);
    }
    __syncthreads();  // staging (incl. Q on first iter) complete

    if (c == 0) {
#pragma unroll
      for (int kk = 0; kk < 2; ++kk) {
        int row = w * 16 + c16;
        aq[kk] = *(const bf16x8*)((const char*)sQ + row * 128 +
                                  ((kk * 64 + g16) ^ ((row & 7) << 4)));
      }
    }

    // S = Q * K^T (per-wave 16 q-rows x 64 keys)
    f32x4 sf[4];
#pragma unroll
    for (int n = 0; n < 4; ++n) {
      f32x4 z = (f32x4){0.f, 0.f, 0.f, 0.f};
#pragma unroll
      for (int kk = 0; kk < 2; ++kk) {
        int row = n * 16 + c16;
        bf16x8 bk = *(const bf16x8*)((const char*)sK + row * 128 +
                                     ((kk * 64 + g16) ^ ((row & 7) << 4)));
        z = MFMA16(aq[kk], bk, z);
      }
      sf[n] = z;
    }

    // online softmax: rows (l>>4)*4+j, keys spread across 16 lanes x 4 n-tiles
#pragma unroll
    for (int n = 0; n < 4; ++n)
#pragma unroll
      for (int j = 0; j < 4; ++j) sf[n][j] *= 0.125f;

#pragma unroll
    for (int j = 0; j < 4; ++j) {
      float mx = fmaxf(fmaxf(sf[0][j], sf[1][j]), fmaxf(sf[2][j], sf[3][j]));
#pragma unroll
      for (int d = 1; d < 16; d <<= 1) mx = fmaxf(mx, __shfl_xor(mx, d));
      float mnew = fmaxf(m_run[j], mx);
      float corr = __expf(m_run[j] - mnew);
      float ps = 0.f;
#pragma unroll
      for (int n = 0; n < 4; ++n) {
        float p = __expf(sf[n][j] - mnew);
        sf[n][j] = p;
        ps += p;
      }
#pragma unroll
      for (int d = 1; d < 16; d <<= 1) ps += __shfl_xor(ps, d);
      l_run[j] = l_run[j] * corr + ps;
      m_run[j] = mnew;
#pragma unroll
      for (int n = 0; n < 4; ++n) of[n][j] *= corr;
    }

    // P (bf16) -> per-wave LDS scratch (swizzled), then PV
    char* sPw = (char*)&sP[w][0];
#pragma unroll
    for (int j = 0; j < 4; ++j) {
      int prow = (l >> 4) * 4 + j;
      int swz = (prow & 7) << 4;
#pragma unroll
      for (int n = 0; n < 4; ++n) {
        int pcol = n * 16 + c16;
        *(u16*)(sPw + prow * 128 + ((pcol * 2) ^ swz)) = f2bf(sf[n][j]);
      }
    }
#pragma unroll
    for (int kk = 0; kk < 2; ++kk) {
      int arow = c16;
      bf16x8 ap = *(const bf16x8*)(sPw + arow * 128 +
                                   ((kk * 64 + g16) ^ ((arow & 7) << 4)));
#pragma unroll
      for (int n = 0; n < 4; ++n) {
        int vrow = n * 16 + c16;
        bf16x8 bv = *(const bf16x8*)((const char*)sVT + vrow * 128 +
                                     ((kk * 64 + g16) ^ ((vrow & 7) << 4)));
        of[n] = MFMA16(ap, bv, of[n]);
      }
    }
  }

  // epilogue: normalize by l_run and store ctx[b*512+row][h*64+dv]
#pragma unroll
  for (int j = 0; j < 4; ++j) {
    float inv = 1.0f / l_run[j];
    int grow = qt * 64 + w * 16 + (l >> 4) * 4 + j;
#pragma unroll
    for (int n = 0; n < 4; ++n) {
      int gcol = h * 64 + n * 16 + c16;
      ctx[(size_t)(b * 512 + grow) * 1024 + gcol] = f2bf(of[n][j] * inv);
    }
  }
}

// ---------------- in-place LayerNorm over D=1024 ---------------------------
__global__ __launch_bounds__(256) void ln_kernel(float* __restrict__ x,
                                                 const float* __restrict__ gamma,
                                                 const float* __restrict__ beta) {
  __shared__ float red[4];
  __shared__ float red2[4];
  int row = blockIdx.x, tid = threadIdx.x;
  float4 v = *(float4*)(x + (size_t)row * 1024 + tid * 4);
  float s = v.x + v.y + v.z + v.w;
#pragma unroll
  for (int d = 1; d < 64; d <<= 1) s += __shfl_xor(s, d);
  if ((tid & 63) == 0) red[tid >> 6] = s;
  __syncthreads();
  float mu = (red[0] + red[1] + red[2] + red[3]) * (1.0f / 1024.0f);
  float d0 = v.x - mu, d1 = v.y - mu, d2 = v.z - mu, d3 = v.w - mu;
  float qq = d0 * d0 + d1 * d1 + d2 * d2 + d3 * d3;
#pragma unroll
  for (int d = 1; d < 64; d <<= 1) qq += __shfl_xor(qq, d);
  if ((tid & 63) == 0) red2[tid >> 6] = qq;
  __syncthreads();
  float var = (red2[0] + red2[1] + red2[2] + red2[3]) * (1.0f / 1024.0f);
  float rstd = rsqrtf(var + 1e-6f);
  float4 g = *(const float4*)(gamma + tid * 4);
  float4 bb = *(const float4*)(beta + tid * 4);
  v.x = g.x * d0 * rstd + bb.x;
  v.y = g.y * d1 * rstd + bb.y;
  v.z = g.z * d2 * rstd + bb.z;
  v.w = g.w * d3 * rstd + bb.w;
  *(float4*)(x + (size_t)row * 1024 + tid * 4) = v;
}

extern "C" void kernel_launch(void* const* d_in, const int* in_sizes, int n_in,
                              void* d_out, int out_size, void* d_ws, size_t ws_size,
                              hipStream_t stream) {
  (void)in_sizes; (void)n_in; (void)out_size; (void)ws_size;
  const float* v_in  = (const float*)d_in[0];
  const float* s_in  = (const float*)d_in[1];
  const float* W_lv  = (const float*)d_in[2];
  const float* b_lv  = (const float*)d_in[3];
  const float* W_ls  = (const float*)d_in[4];
  const float* b_ls  = (const float*)d_in[5];
  const float* pos_v = (const float*)d_in[6];
  // d_in[7] = pos_s (unused), d_in[10]/[11] = W_k/b_k (computed-then-discarded in ref -> skipped)
  const float* W_q   = (const float*)d_in[8];
  const float* b_q   = (const float*)d_in[9];
  const float* W_v   = (const float*)d_in[12];
  const float* b_v   = (const float*)d_in[13];
  const float* W_p   = (const float*)d_in[14];
  const float* b_p   = (const float*)d_in[15];
  const float* gamma = (const float*)d_in[16];
  const float* beta  = (const float*)d_in[17];
  float* out = (float*)d_out;

  char* ws = (char*)d_ws;
  size_t off = 0;
  auto alloc = [&](size_t bytes) {
    char* p = ws + off;
    off += (bytes + 255) & ~(size_t)255;
    return p;
  };
  u16*   v_bf     = (u16*)alloc(33554432);   // [8192][2048] bf16
  u16*   s_bf     = (u16*)alloc(12582912);   // [8192][768]
  u16*   Wlv_t    = (u16*)alloc(4194304);    // [1024][2048]
  u16*   Wls_t    = (u16*)alloc(1572864);    // [1024][768]
  u16*   Wq_t     = (u16*)alloc(2097152);    // [1024][1024]
  u16*   Wv_t     = (u16*)alloc(2097152);
  u16*   Wp_t     = (u16*)alloc(2097152);
  u16*   vproj_bf = (u16*)alloc(16777216);   // [8192][1024]
  float* vproj_f  = (float*)alloc(33554432); // [8192][1024] f32 (residual)
  u16*   sproj_bf = (u16*)alloc(16777216);
  u16*   vsT_bf   = (u16*)alloc(16777216);   // [BH][64][512]
  u16*   ctx_bf   = (u16*)alloc(16777216);   // [8192][1024]
  // aliases into v_bf (dead after gemm1): q [BH][512][64], vs [BH][512][64]
  u16* q_bf  = v_bf;
  u16* vs_bf = v_bf + 8388608;

  cvt_f32_bf16<<<8192, 256, 0, stream>>>(v_in, v_bf, 2097152);
  cvt_f32_bf16<<<3072, 256, 0, stream>>>(s_in, s_bf, 786432);
  wt_cvt_t<<<512, 256, 0, stream>>>(W_lv, Wlv_t, 2048, 1024);
  wt_cvt_t<<<192, 256, 0, stream>>>(W_ls, Wls_t, 768, 1024);
  wt_cvt_t<<<256, 256, 0, stream>>>(W_q, Wq_t, 1024, 1024);
  wt_cvt_t<<<256, 256, 0, stream>>>(W_v, Wv_t, 1024, 1024);
  wt_cvt_t<<<256, 256, 0, stream>>>(W_p, Wp_t, 1024, 1024);

  gemm_bf16<0><<<512, 256, 0, stream>>>(v_bf, Wlv_t, b_lv, vproj_bf, vproj_f,
                                        nullptr, nullptr, 8192, 1024, 2048);
  gemm_bf16<1><<<512, 256, 0, stream>>>(s_bf, Wls_t, b_ls, sproj_bf, nullptr,
                                        nullptr, nullptr, 8192, 1024, 768);
  gemm_bf16<2><<<512, 256, 0, stream>>>(vproj_bf, Wq_t, b_q, q_bf, nullptr,
                                        nullptr, nullptr, 8192, 1024, 1024);
  gemm_bf16<2><<<512, 256, 0, stream>>>(sproj_bf, Wv_t, b_v, vs_bf, nullptr,
                                        nullptr, nullptr, 8192, 1024, 1024);
  vs_transpose<<<2048, 256, 0, stream>>>(vs_bf, vsT_bf);
  attn_kernel<<<2048, 256, 0, stream>>>(q_bf, vs_bf, vsT_bf, ctx_bf);
  gemm_bf16<3><<<512, 256, 0, stream>>>(ctx_bf, Wp_t, b_p, nullptr, out,
                                        vproj_f, pos_v, 8192, 1024, 1024);
  ln_kernel<<<8192, 256, 0, stream>>>(out, gamma, beta);
}

// Round 2
// 258.285 us; speedup vs baseline: 1.0926x; 1.0926x over previous
//
#include <hip/hip_runtime.h>

typedef unsigned short u16;
typedef unsigned int   u32;

using bf16x8 = __attribute__((ext_vector_type(8))) short;
using f32x4  = __attribute__((ext_vector_type(4))) float;

#define MFMA16(a, b, c) __builtin_amdgcn_mfma_f32_16x16x32_bf16((a), (b), (c), 0, 0, 0)

__device__ __forceinline__ u16 f2bf(float f) {
  union { float f; u32 u; } x; x.f = f;
  u32 r = x.u + 0x7fffu + ((x.u >> 16) & 1u);
  return (u16)(r >> 16);
}

// packed f32x2 -> bf16x2 (RNE), single instruction; no builtin on gfx950
__device__ __forceinline__ u32 cvtpk(float lo, float hi) {
  u32 r;
  asm("v_cvt_pk_bf16_f32 %0, %1, %2" : "=v"(r) : "v"(lo), "v"(hi));
  return r;
}

// async global->LDS, 16B per lane; LDS dest must be wave-uniform base (HW adds lane*16)
__device__ __forceinline__ void gl2lds16(const void* g, void* l) {
  __builtin_amdgcn_global_load_lds(
      (const __attribute__((address_space(1))) u32*)g,
      (__attribute__((address_space(3))) u32*)l, 16, 0, 0);
}

// ---------------- fp32 -> bf16 elementwise (8 elems/thread) ----------------
__global__ __launch_bounds__(256) void cvt_f32_bf16(const float* __restrict__ in,
                                                    u16* __restrict__ out, long n8) {
  long i = (long)blockIdx.x * 256 + threadIdx.x;
  if (i >= n8) return;
  const float4* p = (const float4*)(in + i * 8);
  float4 a = p[0], b = p[1];
  u16 t[8] __attribute__((aligned(16)));
  t[0] = f2bf(a.x); t[1] = f2bf(a.y); t[2] = f2bf(a.z); t[3] = f2bf(a.w);
  t[4] = f2bf(b.x); t[5] = f2bf(b.y); t[6] = f2bf(b.z); t[7] = f2bf(b.w);
  *(uint4*)(out + i * 8) = *(uint4*)t;
}

// ---------------- weight convert + transpose: W[K][N] f32 -> Wt[N][K] bf16 --
__global__ __launch_bounds__(256) void wt_cvt_t(const float* __restrict__ W,
                                                u16* __restrict__ Wt, int K, int N) {
  __shared__ u16 t[64][66];
  int tilesN = N >> 6;
  int k0 = ((int)blockIdx.x / tilesN) << 6;
  int n0 = ((int)blockIdx.x % tilesN) << 6;
  int tid = threadIdx.x;
  int c4 = (tid & 15) * 4, r16 = tid >> 4;
#pragma unroll
  for (int p = 0; p < 4; ++p) {
    int row = r16 + p * 16;
    float4 f = *(const float4*)(W + (size_t)(k0 + row) * N + n0 + c4);
    t[row][c4 + 0] = f2bf(f.x);
    t[row][c4 + 1] = f2bf(f.y);
    t[row][c4 + 2] = f2bf(f.z);
    t[row][c4 + 3] = f2bf(f.w);
  }
  __syncthreads();
  int c8 = (tid & 7) * 8, r32 = tid >> 3;
#pragma unroll
  for (int p = 0; p < 2; ++p) {
    int n = r32 + p * 32;
    u16 tmp[8] __attribute__((aligned(16)));
#pragma unroll
    for (int e = 0; e < 8; ++e) tmp[e] = t[c8 + e][n];
    *(uint4*)(Wt + (size_t)(n0 + n) * K + k0 + c8) = *(uint4*)tmp;
  }
}

// ---------------- bf16 batched transpose: vs[BH][512][64] -> vsT[BH][64][512]
__global__ __launch_bounds__(256) void vs_transpose(const u16* __restrict__ vs,
                                                    u16* __restrict__ vsT) {
  __shared__ u16 t[64][66];
  int bh = blockIdx.x >> 3, lt = blockIdx.x & 7;
  int tid = threadIdx.x;
  int c8 = (tid & 7) * 8, r32 = tid >> 3;
  const u16* src = vs + (size_t)bh * 32768 + (size_t)lt * 4096;
#pragma unroll
  for (int p = 0; p < 2; ++p) {
    int row = r32 + p * 32;
    uint4 d = *(const uint4*)(src + (size_t)row * 64 + c8);
    u16 tmp[8] __attribute__((aligned(16)));
    *(uint4*)tmp = d;
#pragma unroll
    for (int e = 0; e < 8; ++e) t[row][c8 + e] = tmp[e];
  }
  __syncthreads();
  u16* dst = vsT + (size_t)bh * 32768 + lt * 64;
#pragma unroll
  for (int p = 0; p < 2; ++p) {
    int dv = r32 + p * 32;
    u16 tmp[8] __attribute__((aligned(16)));
#pragma unroll
    for (int e = 0; e < 8; ++e) tmp[e] = t[c8 + e][dv];
    *(uint4*)(dst + (size_t)dv * 512 + c8) = *(uint4*)tmp;
  }
}

// ---------------- MFMA GEMM: C[M][N] = A[M][K] * Bt[N][K]^T + bias ---------
// 128x128 tile, BK=64, 4 waves (2x2), 64x64 per wave, XOR-swizzled LDS.
template <int MODE>
__global__ __launch_bounds__(256) void gemm_bf16(
    const u16* __restrict__ A, const u16* __restrict__ Bt,
    const float* __restrict__ bias, u16* __restrict__ outb, float* __restrict__ outf,
    const float* __restrict__ add0, const float* __restrict__ add1,
    int M, int N, int K) {
  __shared__ u16 sA[128 * 64];
  __shared__ u16 sB[128 * 64];
  int tilesN = N >> 7;
  int tm = (int)blockIdx.x / tilesN, tn = (int)blockIdx.x % tilesN;
  int m0 = tm << 7, n0 = tn << 7;
  int tid = threadIdx.x, w = tid >> 6, l = tid & 63;
  int wm = (w >> 1) << 6, wn = (w & 1) << 6;
  int c16 = l & 15, g16 = (l >> 4) * 16;

  f32x4 acc[4][4];
#pragma unroll
  for (int i = 0; i < 4; ++i)
#pragma unroll
    for (int j = 0; j < 4; ++j) acc[i][j] = (f32x4){0.f, 0.f, 0.f, 0.f};

  int nk = K >> 6;
  for (int kt = 0; kt < nk; ++kt) {
    __syncthreads();
    const u16* Ab = A + (size_t)m0 * K + kt * 64;
    const u16* Bb = Bt + (size_t)n0 * K + kt * 64;
#pragma unroll
    for (int j = 0; j < 4; ++j) {
      int chunk = w * 4 + j;
      int lin = chunk * 1024 + l * 16;
      int row = lin >> 7;
      int cb = (lin & 127) ^ ((row & 7) << 4);
      gl2lds16(Ab + (size_t)row * K + (cb >> 1), (char*)sA + chunk * 1024);
      gl2lds16(Bb + (size_t)row * K + (cb >> 1), (char*)sB + chunk * 1024);
    }
    __syncthreads();
#pragma unroll
    for (int kk = 0; kk < 2; ++kk) {
      bf16x8 af[4], bfr[4];
#pragma unroll
      for (int i = 0; i < 4; ++i) {
        int ar = wm + i * 16 + c16;
        af[i] = *(const bf16x8*)((const char*)sA + ar * 128 +
                                 ((kk * 64 + g16) ^ ((ar & 7) << 4)));
        int br = wn + i * 16 + c16;
        bfr[i] = *(const bf16x8*)((const char*)sB + br * 128 +
                                  ((kk * 64 + g16) ^ ((br & 7) << 4)));
      }
#pragma unroll
      for (int i = 0; i < 4; ++i)
#pragma unroll
        for (int j = 0; j < 4; ++j) acc[i][j] = MFMA16(af[i], bfr[j], acc[i][j]);
    }
  }
#pragma unroll
  for (int i = 0; i < 4; ++i) {
#pragma unroll
    for (int j = 0; j < 4; ++j) {
#pragma unroll
      for (int r = 0; r < 4; ++r) {
        int gm = m0 + wm + i * 16 + (l >> 4) * 4 + r;
        int gn = n0 + wn + j * 16 + c16;
        float v = acc[i][j][r] + bias[gn];
        if (MODE == 0) {
          v = fmaxf(v, 0.f);
          outb[(size_t)gm * N + gn] = f2bf(v);
          outf[(size_t)gm * N + gn] = v;
        } else if (MODE == 1) {
          v = fmaxf(v, 0.f);
          outb[(size_t)gm * N + gn] = f2bf(v);
        } else if (MODE == 2) {
          int hh = gn >> 6, dk = gn & 63, bb2 = gm >> 9, ll2 = gm & 511;
          outb[(((size_t)bb2 * 16 + hh) * 512 + ll2) * 64 + dk] = f2bf(v);
        } else {
          v += add0[(size_t)gm * N + gn] + add1[(size_t)(gm & 511) * N + gn];
          outf[(size_t)gm * N + gn] = v;
        }
      }
    }
  }
}

// ---------------- fused attention: swapped-QK^T + swapped-PV ---------------
// q[BH][512][64], kv[BH][512][64], kvT[BH][64][512] bf16; ctx[B*512][1024] bf16
// 8 waves, QBLK=128 (wave w owns q-rows w*16..+16; lane owns q-row w*16+c16).
// S^T = mfma(K,Q): lane holds S[key 16-strided set][its q-row] -> in-lane softmax.
// O^T = mfma(V^T,P): lane accumulates O[its q-row][dv subsets].
__global__ __launch_bounds__(512) void attn_kernel(const u16* __restrict__ q,
                                                   const u16* __restrict__ kv,
                                                   const u16* __restrict__ kvT,
                                                   u16* __restrict__ ctx) {
  __shared__ u16 sK[2][4096];   // [64 keys][64 dk], 128B rows, XOR swizzle
  __shared__ u16 sVT[2][4096];  // [64 dv][64 keys]
  __shared__ u16 sP[8192];      // Q staging (128x64), then per-wave P (16x64 each)

  // bijective XCD-chunked swizzle: same-bh blocks co-locate on one XCD
  int orig = (int)blockIdx.x;
  int r = (orig & 7) * 128 + (orig >> 3);
  int bh = r >> 2, qt = r & 3;
  int b = bh >> 4, h = bh & 15;
  int tid = threadIdx.x, w = tid >> 6, l = tid & 63;
  int c16 = l & 15, hi = l >> 4, g16 = hi * 16;
  int swzq = (c16 & 7) << 4;

  // stage Q tile (128x64) into sP; wave w fills rows 16w..16w+15 (its own P region)
  const u16* qbase = q + (size_t)bh * 32768 + (size_t)qt * 8192;
#pragma unroll
  for (int j = 0; j < 2; ++j) {
    int chunk = w * 2 + j;
    int lin = chunk * 1024 + l * 16;
    int row = lin >> 7;
    int cb = (lin & 127) ^ ((row & 7) << 4);
    gl2lds16(qbase + (size_t)row * 64 + (cb >> 1), (char*)sP + chunk * 1024);
  }
  // stage K/VT chunk 0 into buf 0
  {
    const u16* kb = kv + (size_t)bh * 32768;
    const u16* vb = kvT + (size_t)bh * 32768;
    int lin = w * 1024 + l * 16;
    int row = lin >> 7;
    int cb = (lin & 127) ^ ((row & 7) << 4);
    gl2lds16(kb + (size_t)row * 64 + (cb >> 1), (char*)sK[0] + w * 1024);
    gl2lds16(vb + (size_t)row * 512 + (cb >> 1), (char*)sVT[0] + w * 1024);
  }
  __syncthreads();

  // Q fragments (lane's q-row = w*16 + c16), row&7 == c16&7
  const char* sQrow = (const char*)sP + (w * 16 + c16) * 128;
  bf16x8 qf0 = *(const bf16x8*)(sQrow + ((0 + g16) ^ swzq));
  bf16x8 qf1 = *(const bf16x8*)(sQrow + ((64 + g16) ^ swzq));

  char* sPw = (char*)sP + w * 2048;
  f32x4 of[4];
#pragma unroll
  for (int n = 0; n < 4; ++n) of[n] = (f32x4){0.f, 0.f, 0.f, 0.f};
  float m_run = -1e30f, l_run = 0.f;

  for (int c = 0; c < 8; ++c) {
    int cur = c & 1;
    if (c < 7) {  // prefetch next chunk into other buffer
      const u16* kb = kv + (size_t)bh * 32768 + (size_t)(c + 1) * 4096;
      const u16* vb = kvT + (size_t)bh * 32768 + (c + 1) * 64;
      int lin = w * 1024 + l * 16;
      int row = lin >> 7;
      int cb = (lin & 127) ^ ((row & 7) << 4);
      gl2lds16(kb + (size_t)row * 64 + (cb >> 1), (char*)sK[cur ^ 1] + w * 1024);
      gl2lds16(vb + (size_t)row * 512 + (cb >> 1), (char*)sVT[cur ^ 1] + w * 1024);
    }
    const char* kbuf = (const char*)sK[cur];
    const char* vtbuf = (const char*)sVT[cur];

    // S^T: lane -> S[key = n*16 + hi*4 + r][q-row = c16 (within wave)]
    f32x4 sf[4];
#pragma unroll
    for (int n = 0; n < 4; ++n) {
      const char* krow = kbuf + (n * 16 + c16) * 128;  // key-row, (row&7)==(c16&7)
      bf16x8 k0 = *(const bf16x8*)(krow + (g16 ^ swzq));
      bf16x8 k1 = *(const bf16x8*)(krow + ((64 + g16) ^ swzq));
      f32x4 z = (f32x4){0.f, 0.f, 0.f, 0.f};
      z = MFMA16(k0, qf0, z);
      z = MFMA16(k1, qf1, z);
      sf[n] = z;
    }

    // in-lane online softmax (one q-row per lane; 16 keys here, 64 across 4 lanes)
    float pmax = -1e30f;
#pragma unroll
    for (int n = 0; n < 4; ++n)
#pragma unroll
      for (int rr = 0; rr < 4; ++rr) {
        sf[n][rr] *= 0.125f;
        pmax = fmaxf(pmax, sf[n][rr]);
      }
    pmax = fmaxf(pmax, __shfl_xor(pmax, 16));
    pmax = fmaxf(pmax, __shfl_xor(pmax, 32));
    float mnew = fmaxf(m_run, pmax);
    float corr = __expf(m_run - mnew);
    float psum = 0.f;
#pragma unroll
    for (int n = 0; n < 4; ++n)
#pragma unroll
      for (int rr = 0; rr < 4; ++rr) {
        float p = __expf(sf[n][rr] - mnew);
        sf[n][rr] = p;
        psum += p;
      }
    psum += __shfl_xor(psum, 16);
    psum += __shfl_xor(psum, 32);
    l_run = l_run * corr + psum;
    m_run = mnew;
#pragma unroll
    for (int n = 0; n < 4; ++n)
#pragma unroll
      for (int rr = 0; rr < 4; ++rr) of[n][rr] *= corr;

    // P -> per-wave LDS (row = lane's q-row c16; keys n*16+hi*4+{0..3} adjacent)
#pragma unroll
    for (int n = 0; n < 4; ++n) {
      uint2 pw;
      pw.x = cvtpk(sf[n][0], sf[n][1]);
      pw.y = cvtpk(sf[n][2], sf[n][3]);
      *(uint2*)(sPw + c16 * 128 + ((n * 32 + hi * 8) ^ swzq)) = pw;
    }

    // PV (swapped): of[n] += V^T[dv-tile n] * P ; B-frag = lane's own P row
    bf16x8 pf0 = *(const bf16x8*)(sPw + c16 * 128 + (g16 ^ swzq));
    bf16x8 pf1 = *(const bf16x8*)(sPw + c16 * 128 + ((64 + g16) ^ swzq));
#pragma unroll
    for (int n = 0; n < 4; ++n) {
      const char* vrow = vtbuf + (n * 16 + c16) * 128;
      bf16x8 v0 = *(const bf16x8*)(vrow + (g16 ^ swzq));
      bf16x8 v1 = *(const bf16x8*)(vrow + ((64 + g16) ^ swzq));
      of[n] = MFMA16(v0, pf0, of[n]);
      of[n] = MFMA16(v1, pf1, of[n]);
    }
    __syncthreads();  // next buffer staged; all waves done with current buffer
  }

  // epilogue: O[q=grow][dv = n*16 + hi*4 + r] scaled by 1/l_run
  float inv = 1.0f / l_run;
  int grow = qt * 128 + w * 16 + c16;
  u16* obase = ctx + (size_t)(b * 512 + grow) * 1024 + h * 64;
#pragma unroll
  for (int n = 0; n < 4; ++n) {
    uint2 ow;
    ow.x = cvtpk(of[n][0] * inv, of[n][1] * inv);
    ow.y = cvtpk(of[n][2] * inv, of[n][3] * inv);
    *(uint2*)(obase + n * 16 + hi * 4) = ow;
  }
}

// ---------------- in-place LayerNorm over D=1024 ---------------------------
__global__ __launch_bounds__(256) void ln_kernel(float* __restrict__ x,
                                                 const float* __restrict__ gamma,
                                                 const float* __restrict__ beta) {
  __shared__ float red[4];
  __shared__ float red2[4];
  int row = blockIdx.x, tid = threadIdx.x;
  float4 v = *(float4*)(x + (size_t)row * 1024 + tid * 4);
  float s = v.x + v.y + v.z + v.w;
#pragma unroll
  for (int d = 1; d < 64; d <<= 1) s += __shfl_xor(s, d);
  if ((tid & 63) == 0) red[tid >> 6] = s;
  __syncthreads();
  float mu = (red[0] + red[1] + red[2] + red[3]) * (1.0f / 1024.0f);
  float d0 = v.x - mu, d1 = v.y - mu, d2 = v.z - mu, d3 = v.w - mu;
  float qq = d0 * d0 + d1 * d1 + d2 * d2 + d3 * d3;
#pragma unroll
  for (int d = 1; d < 64; d <<= 1) qq += __shfl_xor(qq, d);
  if ((tid & 63) == 0) red2[tid >> 6] = qq;
  __syncthreads();
  float var = (red2[0] + red2[1] + red2[2] + red2[3]) * (1.0f / 1024.0f);
  float rstd = rsqrtf(var + 1e-6f);
  float4 g = *(const float4*)(gamma + tid * 4);
  float4 bb = *(const float4*)(beta + tid * 4);
  v.x = g.x * d0 * rstd + bb.x;
  v.y = g.y * d1 * rstd + bb.y;
  v.z = g.z * d2 * rstd + bb.z;
  v.w = g.w * d3 * rstd + bb.w;
  *(float4*)(x + (size_t)row * 1024 + tid * 4) = v;
}

extern "C" void kernel_launch(void* const* d_in, const int* in_sizes, int n_in,
                              void* d_out, int out_size, void* d_ws, size_t ws_size,
                              hipStream_t stream) {
  (void)in_sizes; (void)n_in; (void)out_size; (void)ws_size;
  const float* v_in  = (const float*)d_in[0];
  const float* s_in  = (const float*)d_in[1];
  const float* W_lv  = (const float*)d_in[2];
  const float* b_lv  = (const float*)d_in[3];
  const float* W_ls  = (const float*)d_in[4];
  const float* b_ls  = (const float*)d_in[5];
  const float* pos_v = (const float*)d_in[6];
  // d_in[7] = pos_s (unused), d_in[10]/[11] = W_k/b_k (discarded in ref)
  const float* W_q   = (const float*)d_in[8];
  const float* b_q   = (const float*)d_in[9];
  const float* W_v   = (const float*)d_in[12];
  const float* b_v   = (const float*)d_in[13];
  const float* W_p   = (const float*)d_in[14];
  const float* b_p   = (const float*)d_in[15];
  const float* gamma = (const float*)d_in[16];
  const float* beta  = (const float*)d_in[17];
  float* out = (float*)d_out;

  char* ws = (char*)d_ws;
  size_t off = 0;
  auto alloc = [&](size_t bytes) {
    char* p = ws + off;
    off += (bytes + 255) & ~(size_t)255;
    return p;
  };
  u16*   v_bf     = (u16*)alloc(33554432);
  u16*   s_bf     = (u16*)alloc(12582912);
  u16*   Wlv_t    = (u16*)alloc(4194304);
  u16*   Wls_t    = (u16*)alloc(1572864);
  u16*   Wq_t     = (u16*)alloc(2097152);
  u16*   Wv_t     = (u16*)alloc(2097152);
  u16*   Wp_t     = (u16*)alloc(2097152);
  u16*   vproj_bf = (u16*)alloc(16777216);
  float* vproj_f  = (float*)alloc(33554432);
  u16*   sproj_bf = (u16*)alloc(16777216);
  u16*   vsT_bf   = (u16*)alloc(16777216);
  u16*   ctx_bf   = (u16*)alloc(16777216);
  u16* q_bf  = v_bf;
  u16* vs_bf = v_bf + 8388608;

  cvt_f32_bf16<<<8192, 256, 0, stream>>>(v_in, v_bf, 2097152);
  cvt_f32_bf16<<<3072, 256, 0, stream>>>(s_in, s_bf, 786432);
  wt_cvt_t<<<512, 256, 0, stream>>>(W_lv, Wlv_t, 2048, 1024);
  wt_cvt_t<<<192, 256, 0, stream>>>(W_ls, Wls_t, 768, 1024);
  wt_cvt_t<<<256, 256, 0, stream>>>(W_q, Wq_t, 1024, 1024);
  wt_cvt_t<<<256, 256, 0, stream>>>(W_v, Wv_t, 1024, 1024);
  wt_cvt_t<<<256, 256, 0, stream>>>(W_p, Wp_t, 1024, 1024);

  gemm_bf16<0><<<512, 256, 0, stream>>>(v_bf, Wlv_t, b_lv, vproj_bf, vproj_f,
                                        nullptr, nullptr, 8192, 1024, 2048);
  gemm_bf16<1><<<512, 256, 0, stream>>>(s_bf, Wls_t, b_ls, sproj_bf, nullptr,
                                        nullptr, nullptr, 8192, 1024, 768);
  gemm_bf16<2><<<512, 256, 0, stream>>>(vproj_bf, Wq_t, b_q, q_bf, nullptr,
                                        nullptr, nullptr, 8192, 1024, 1024);
  gemm_bf16<2><<<512, 256, 0, stream>>>(sproj_bf, Wv_t, b_v, vs_bf, nullptr,
                                        nullptr, nullptr, 8192, 1024, 1024);
  vs_transpose<<<2048, 256, 0, stream>>>(vs_bf, vsT_bf);
  attn_kernel<<<1024, 512, 0, stream>>>(q_bf, vs_bf, vsT_bf, ctx_bf);
  gemm_bf16<3><<<512, 256, 0, stream>>>(ctx_bf, Wp_t, b_p, nullptr, out,
                                        vproj_f, pos_v, 8192, 1024, 1024);
  ln_kernel<<<8192, 256, 0, stream>>>(out, gamma, beta);
}

// Round 3
// 241.135 us; speedup vs baseline: 1.1703x; 1.0711x over previous
//
#include <hip/hip_runtime.h>

typedef unsigned short u16;
typedef unsigned int   u32;

using bf16x8 = __attribute__((ext_vector_type(8))) short;
using f32x4  = __attribute__((ext_vector_type(4))) float;

#define MFMA16(a, b, c) __builtin_amdgcn_mfma_f32_16x16x32_bf16((a), (b), (c), 0, 0, 0)

__device__ __forceinline__ u16 f2bf(float f) {
  union { float f; u32 u; } x; x.f = f;
  u32 r = x.u + 0x7fffu + ((x.u >> 16) & 1u);
  return (u16)(r >> 16);
}

__device__ __forceinline__ float bf2f(u16 v) {
  union { u32 u; float f; } x; x.u = ((u32)v) << 16;
  return x.f;
}

// packed f32x2 -> bf16x2 (RNE), single instruction; no builtin on gfx950
__device__ __forceinline__ u32 cvtpk(float lo, float hi) {
  u32 r;
  asm("v_cvt_pk_bf16_f32 %0, %1, %2" : "=v"(r) : "v"(lo), "v"(hi));
  return r;
}

// async global->LDS, 16B per lane; LDS dest must be wave-uniform base (HW adds lane*16)
__device__ __forceinline__ void gl2lds16(const void* g, void* l) {
  __builtin_amdgcn_global_load_lds(
      (const __attribute__((address_space(1))) u32*)g,
      (__attribute__((address_space(3))) u32*)l, 16, 0, 0);
}

// ---------------- weight convert + transpose: W[K][N] f32 -> Wt[N][K] bf16 --
__global__ __launch_bounds__(256) void wt_cvt_t(const float* __restrict__ W,
                                                u16* __restrict__ Wt, int K, int N) {
  __shared__ u16 t[64][66];
  int tilesN = N >> 6;
  int k0 = ((int)blockIdx.x / tilesN) << 6;
  int n0 = ((int)blockIdx.x % tilesN) << 6;
  int tid = threadIdx.x;
  int c4 = (tid & 15) * 4, r16 = tid >> 4;
#pragma unroll
  for (int p = 0; p < 4; ++p) {
    int row = r16 + p * 16;
    float4 f = *(const float4*)(W + (size_t)(k0 + row) * N + n0 + c4);
    t[row][c4 + 0] = f2bf(f.x);
    t[row][c4 + 1] = f2bf(f.y);
    t[row][c4 + 2] = f2bf(f.z);
    t[row][c4 + 3] = f2bf(f.w);
  }
  __syncthreads();
  int c8 = (tid & 7) * 8, r32 = tid >> 3;
#pragma unroll
  for (int p = 0; p < 2; ++p) {
    int n = r32 + p * 32;
    u16 tmp[8] __attribute__((aligned(16)));
#pragma unroll
    for (int e = 0; e < 8; ++e) tmp[e] = t[c8 + e][n];
    *(uint4*)(Wt + (size_t)(n0 + n) * K + k0 + c8) = *(uint4*)tmp;
  }
}

// ---------------- MFMA GEMM: C[M][N] = A[M][K] * Bt[N][K]^T + bias ---------
// 128x128 tile, BK=64, 4 waves (2x2), 64x64 per wave, XOR-swizzled LDS.
// AF32: A is f32, converted to bf16 during reg-staged LDS fill (fused cvt).
// MODE 0: relu, write bf16
// MODE 2: write bf16 permuted to [B][H][L][64] (q-proj)
// MODE 4: like 2, plus transposed write [BH][64][512] (vs-proj, fused transpose)
// MODE 3: out = acc + bias + bf2f(add0b[m][n]) + add1[m&511][n], f32 (out-proj)
template <int MODE, bool AF32>
__global__ __launch_bounds__(256) void gemm_bf16(
    const void* __restrict__ Av, const u16* __restrict__ Bt,
    const float* __restrict__ bias, u16* __restrict__ outb, float* __restrict__ outf,
    u16* __restrict__ outt, const u16* __restrict__ add0b,
    const float* __restrict__ add1, int M, int N, int K) {
  __shared__ u16 sA[128 * 64];
  __shared__ u16 sB[128 * 64];
  int tilesN = N >> 7;
  // bijective XCD-chunked swizzle: XCD x owns a contiguous tm range (A stays L2-hot)
  int nwg = (int)gridDim.x;
  int cpx = nwg >> 3;
  int orig = (int)blockIdx.x;
  int wg = (orig & 7) * cpx + (orig >> 3);
  int tm = wg / tilesN, tn = wg % tilesN;
  int m0 = tm << 7, n0 = tn << 7;
  int tid = threadIdx.x, w = tid >> 6, l = tid & 63;
  int wm = (w >> 1) << 6, wn = (w & 1) << 6;
  int c16 = l & 15, g16 = (l >> 4) * 16;

  f32x4 acc[4][4];
#pragma unroll
  for (int i = 0; i < 4; ++i)
#pragma unroll
    for (int j = 0; j < 4; ++j) acc[i][j] = (f32x4){0.f, 0.f, 0.f, 0.f};

  int nk = K >> 6;
  for (int kt = 0; kt < nk; ++kt) {
    __syncthreads();
    const u16* Bb = Bt + (size_t)n0 * K + kt * 64;
    if constexpr (AF32) {
      const float* Af = (const float*)Av;
#pragma unroll
      for (int j = 0; j < 4; ++j) {
        int chunk = w * 4 + j;
        int lin = chunk * 1024 + l * 16;  // linear byte pos in bf16 tile
        int row = lin >> 7;
        int colb = lin & 127;  // byte col within 128B row (pre-swizzle)
        const float* src = Af + (size_t)(m0 + row) * K + kt * 64 + (colb >> 1);
        float4 f0 = *(const float4*)src;
        float4 f1 = *(const float4*)(src + 4);
        uint4 pk;
        pk.x = cvtpk(f0.x, f0.y);
        pk.y = cvtpk(f0.z, f0.w);
        pk.z = cvtpk(f1.x, f1.y);
        pk.w = cvtpk(f1.z, f1.w);
        // swizzle applied on the WRITE side (reg-staged), source stays linear
        *(uint4*)((char*)sA + (lin & ~127) + (colb ^ ((row & 7) << 4))) = pk;
        gl2lds16(Bb + (size_t)row * K + (((lin & 127) ^ ((row & 7) << 4)) >> 1),
                 (char*)sB + chunk * 1024);
      }
    } else {
      const u16* Ab = (const u16*)Av + (size_t)m0 * K + kt * 64;
#pragma unroll
      for (int j = 0; j < 4; ++j) {
        int chunk = w * 4 + j;
        int lin = chunk * 1024 + l * 16;
        int row = lin >> 7;
        int cb = (lin & 127) ^ ((row & 7) << 4);
        gl2lds16(Ab + (size_t)row * K + (cb >> 1), (char*)sA + chunk * 1024);
        gl2lds16(Bb + (size_t)row * K + (cb >> 1), (char*)sB + chunk * 1024);
      }
    }
    __syncthreads();
#pragma unroll
    for (int kk = 0; kk < 2; ++kk) {
      bf16x8 af[4], bfr[4];
#pragma unroll
      for (int i = 0; i < 4; ++i) {
        int ar = wm + i * 16 + c16;
        af[i] = *(const bf16x8*)((const char*)sA + ar * 128 +
                                 ((kk * 64 + g16) ^ ((ar & 7) << 4)));
        int br = wn + i * 16 + c16;
        bfr[i] = *(const bf16x8*)((const char*)sB + br * 128 +
                                  ((kk * 64 + g16) ^ ((br & 7) << 4)));
      }
#pragma unroll
      for (int i = 0; i < 4; ++i)
#pragma unroll
        for (int j = 0; j < 4; ++j) acc[i][j] = MFMA16(af[i], bfr[j], acc[i][j]);
    }
  }
#pragma unroll
  for (int i = 0; i < 4; ++i) {
#pragma unroll
    for (int j = 0; j < 4; ++j) {
      float vv[4];
#pragma unroll
      for (int r = 0; r < 4; ++r) {
        int gn = n0 + wn + j * 16 + c16;
        vv[r] = acc[i][j][r] + bias[gn];
      }
      int gm0 = m0 + wm + i * 16 + (l >> 4) * 4;
      int gn = n0 + wn + j * 16 + c16;
      if (MODE == 0) {
#pragma unroll
        for (int r = 0; r < 4; ++r)
          outb[(size_t)(gm0 + r) * N + gn] = f2bf(fmaxf(vv[r], 0.f));
      } else if (MODE == 2 || MODE == 4) {
        int hh = gn >> 6, dk = gn & 63, bb2 = gm0 >> 9, ll2 = gm0 & 511;
#pragma unroll
        for (int r = 0; r < 4; ++r)
          outb[(((size_t)bb2 * 16 + hh) * 512 + ll2 + r) * 64 + dk] = f2bf(vv[r]);
        if (MODE == 4) {
          uint2 tw;
          tw.x = cvtpk(vv[0], vv[1]);
          tw.y = cvtpk(vv[2], vv[3]);
          *(uint2*)(outt + (((size_t)bb2 * 16 + hh) * 64 + dk) * 512 + ll2) = tw;
        }
      } else {  // MODE 3
#pragma unroll
        for (int r = 0; r < 4; ++r) {
          int gm = gm0 + r;
          float v = vv[r] + bf2f(add0b[(size_t)gm * N + gn]) +
                    add1[(size_t)(gm & 511) * N + gn];
          outf[(size_t)gm * N + gn] = v;
        }
      }
    }
  }
}

// ---------------- fused attention: swapped-QK^T + swapped-PV ---------------
__global__ __launch_bounds__(512) void attn_kernel(const u16* __restrict__ q,
                                                   const u16* __restrict__ kv,
                                                   const u16* __restrict__ kvT,
                                                   u16* __restrict__ ctx) {
  __shared__ u16 sK[2][4096];   // [64 keys][64 dk], 128B rows, XOR swizzle
  __shared__ u16 sVT[2][4096];  // [64 dv][64 keys]
  __shared__ u16 sP[8192];      // Q staging (128x64), then per-wave P (16x64 each)

  int orig = (int)blockIdx.x;
  int r = (orig & 7) * 128 + (orig >> 3);
  int bh = r >> 2, qt = r & 3;
  int b = bh >> 4, h = bh & 15;
  int tid = threadIdx.x, w = tid >> 6, l = tid & 63;
  int c16 = l & 15, hi = l >> 4, g16 = hi * 16;
  int swzq = (c16 & 7) << 4;

  const u16* qbase = q + (size_t)bh * 32768 + (size_t)qt * 8192;
#pragma unroll
  for (int j = 0; j < 2; ++j) {
    int chunk = w * 2 + j;
    int lin = chunk * 1024 + l * 16;
    int row = lin >> 7;
    int cb = (lin & 127) ^ ((row & 7) << 4);
    gl2lds16(qbase + (size_t)row * 64 + (cb >> 1), (char*)sP + chunk * 1024);
  }
  {
    const u16* kb = kv + (size_t)bh * 32768;
    const u16* vb = kvT + (size_t)bh * 32768;
    int lin = w * 1024 + l * 16;
    int row = lin >> 7;
    int cb = (lin & 127) ^ ((row & 7) << 4);
    gl2lds16(kb + (size_t)row * 64 + (cb >> 1), (char*)sK[0] + w * 1024);
    gl2lds16(vb + (size_t)row * 512 + (cb >> 1), (char*)sVT[0] + w * 1024);
  }
  __syncthreads();

  const char* sQrow = (const char*)sP + (w * 16 + c16) * 128;
  bf16x8 qf0 = *(const bf16x8*)(sQrow + ((0 + g16) ^ swzq));
  bf16x8 qf1 = *(const bf16x8*)(sQrow + ((64 + g16) ^ swzq));

  char* sPw = (char*)sP + w * 2048;
  f32x4 of[4];
#pragma unroll
  for (int n = 0; n < 4; ++n) of[n] = (f32x4){0.f, 0.f, 0.f, 0.f};
  float m_run = -1e30f, l_run = 0.f;

  for (int c = 0; c < 8; ++c) {
    int cur = c & 1;
    if (c < 7) {
      const u16* kb = kv + (size_t)bh * 32768 + (size_t)(c + 1) * 4096;
      const u16* vb = kvT + (size_t)bh * 32768 + (c + 1) * 64;
      int lin = w * 1024 + l * 16;
      int row = lin >> 7;
      int cb = (lin & 127) ^ ((row & 7) << 4);
      gl2lds16(kb + (size_t)row * 64 + (cb >> 1), (char*)sK[cur ^ 1] + w * 1024);
      gl2lds16(vb + (size_t)row * 512 + (cb >> 1), (char*)sVT[cur ^ 1] + w * 1024);
    }
    const char* kbuf = (const char*)sK[cur];
    const char* vtbuf = (const char*)sVT[cur];

    f32x4 sf[4];
#pragma unroll
    for (int n = 0; n < 4; ++n) {
      const char* krow = kbuf + (n * 16 + c16) * 128;
      bf16x8 k0 = *(const bf16x8*)(krow + (g16 ^ swzq));
      bf16x8 k1 = *(const bf16x8*)(krow + ((64 + g16) ^ swzq));
      f32x4 z = (f32x4){0.f, 0.f, 0.f, 0.f};
      z = MFMA16(k0, qf0, z);
      z = MFMA16(k1, qf1, z);
      sf[n] = z;
    }

    float pmax = -1e30f;
#pragma unroll
    for (int n = 0; n < 4; ++n)
#pragma unroll
      for (int rr = 0; rr < 4; ++rr) {
        sf[n][rr] *= 0.125f;
        pmax = fmaxf(pmax, sf[n][rr]);
      }
    pmax = fmaxf(pmax, __shfl_xor(pmax, 16));
    pmax = fmaxf(pmax, __shfl_xor(pmax, 32));
    float mnew = fmaxf(m_run, pmax);
    float corr = __expf(m_run - mnew);
    float psum = 0.f;
#pragma unroll
    for (int n = 0; n < 4; ++n)
#pragma unroll
      for (int rr = 0; rr < 4; ++rr) {
        float p = __expf(sf[n][rr] - mnew);
        sf[n][rr] = p;
        psum += p;
      }
    psum += __shfl_xor(psum, 16);
    psum += __shfl_xor(psum, 32);
    l_run = l_run * corr + psum;
    m_run = mnew;
#pragma unroll
    for (int n = 0; n < 4; ++n)
#pragma unroll
      for (int rr = 0; rr < 4; ++rr) of[n][rr] *= corr;

#pragma unroll
    for (int n = 0; n < 4; ++n) {
      uint2 pw;
      pw.x = cvtpk(sf[n][0], sf[n][1]);
      pw.y = cvtpk(sf[n][2], sf[n][3]);
      *(uint2*)(sPw + c16 * 128 + ((n * 32 + hi * 8) ^ swzq)) = pw;
    }

    bf16x8 pf0 = *(const bf16x8*)(sPw + c16 * 128 + (g16 ^ swzq));
    bf16x8 pf1 = *(const bf16x8*)(sPw + c16 * 128 + ((64 + g16) ^ swzq));
#pragma unroll
    for (int n = 0; n < 4; ++n) {
      const char* vrow = vtbuf + (n * 16 + c16) * 128;
      bf16x8 v0 = *(const bf16x8*)(vrow + (g16 ^ swzq));
      bf16x8 v1 = *(const bf16x8*)(vrow + ((64 + g16) ^ swzq));
      of[n] = MFMA16(v0, pf0, of[n]);
      of[n] = MFMA16(v1, pf1, of[n]);
    }
    __syncthreads();
  }

  float inv = 1.0f / l_run;
  int grow = qt * 128 + w * 16 + c16;
  u16* obase = ctx + (size_t)(b * 512 + grow) * 1024 + h * 64;
#pragma unroll
  for (int n = 0; n < 4; ++n) {
    uint2 ow;
    ow.x = cvtpk(of[n][0] * inv, of[n][1] * inv);
    ow.y = cvtpk(of[n][2] * inv, of[n][3] * inv);
    *(uint2*)(obase + n * 16 + hi * 4) = ow;
  }
}

// ---------------- in-place LayerNorm over D=1024 ---------------------------
__global__ __launch_bounds__(256) void ln_kernel(float* __restrict__ x,
                                                 const float* __restrict__ gamma,
                                                 const float* __restrict__ beta) {
  __shared__ float red[4];
  __shared__ float red2[4];
  int row = blockIdx.x, tid = threadIdx.x;
  float4 v = *(float4*)(x + (size_t)row * 1024 + tid * 4);
  float s = v.x + v.y + v.z + v.w;
#pragma unroll
  for (int d = 1; d < 64; d <<= 1) s += __shfl_xor(s, d);
  if ((tid & 63) == 0) red[tid >> 6] = s;
  __syncthreads();
  float mu = (red[0] + red[1] + red[2] + red[3]) * (1.0f / 1024.0f);
  float d0 = v.x - mu, d1 = v.y - mu, d2 = v.z - mu, d3 = v.w - mu;
  float qq = d0 * d0 + d1 * d1 + d2 * d2 + d3 * d3;
#pragma unroll
  for (int d = 1; d < 64; d <<= 1) qq += __shfl_xor(qq, d);
  if ((tid & 63) == 0) red2[tid >> 6] = qq;
  __syncthreads();
  float var = (red2[0] + red2[1] + red2[2] + red2[3]) * (1.0f / 1024.0f);
  float rstd = rsqrtf(var + 1e-6f);
  float4 g = *(const float4*)(gamma + tid * 4);
  float4 bb = *(const float4*)(beta + tid * 4);
  v.x = g.x * d0 * rstd + bb.x;
  v.y = g.y * d1 * rstd + bb.y;
  v.z = g.z * d2 * rstd + bb.z;
  v.w = g.w * d3 * rstd + bb.w;
  *(float4*)(x + (size_t)row * 1024 + tid * 4) = v;
}

extern "C" void kernel_launch(void* const* d_in, const int* in_sizes, int n_in,
                              void* d_out, int out_size, void* d_ws, size_t ws_size,
                              hipStream_t stream) {
  (void)in_sizes; (void)n_in; (void)out_size; (void)ws_size;
  const float* v_in  = (const float*)d_in[0];
  const float* s_in  = (const float*)d_in[1];
  const float* W_lv  = (const float*)d_in[2];
  const float* b_lv  = (const float*)d_in[3];
  const float* W_ls  = (const float*)d_in[4];
  const float* b_ls  = (const float*)d_in[5];
  const float* pos_v = (const float*)d_in[6];
  // d_in[7] = pos_s (unused), d_in[10]/[11] = W_k/b_k (discarded in ref)
  const float* W_q   = (const float*)d_in[8];
  const float* b_q   = (const float*)d_in[9];
  const float* W_v   = (const float*)d_in[12];
  const float* b_v   = (const float*)d_in[13];
  const float* W_p   = (const float*)d_in[14];
  const float* b_p   = (const float*)d_in[15];
  const float* gamma = (const float*)d_in[16];
  const float* beta  = (const float*)d_in[17];
  float* out = (float*)d_out;

  char* ws = (char*)d_ws;
  size_t off = 0;
  auto alloc = [&](size_t bytes) {
    char* p = ws + off;
    off += (bytes + 255) & ~(size_t)255;
    return p;
  };
  u16* Wlv_t    = (u16*)alloc(4194304);    // [1024][2048] bf16
  u16* Wls_t    = (u16*)alloc(1572864);    // [1024][768]
  u16* Wq_t     = (u16*)alloc(2097152);    // [1024][1024]
  u16* Wv_t     = (u16*)alloc(2097152);
  u16* Wp_t     = (u16*)alloc(2097152);
  u16* vproj_bf = (u16*)alloc(16777216);   // [8192][1024] (also the residual, bf16)
  u16* sproj_bf = (u16*)alloc(16777216);
  u16* q_bf     = (u16*)alloc(16777216);   // [BH][512][64]
  u16* vs_bf    = (u16*)alloc(16777216);   // [BH][512][64]
  u16* vsT_bf   = (u16*)alloc(16777216);   // [BH][64][512]
  u16* ctx_bf   = (u16*)alloc(16777216);   // [8192][1024]

  wt_cvt_t<<<512, 256, 0, stream>>>(W_lv, Wlv_t, 2048, 1024);
  wt_cvt_t<<<192, 256, 0, stream>>>(W_ls, Wls_t, 768, 1024);
  wt_cvt_t<<<256, 256, 0, stream>>>(W_q, Wq_t, 1024, 1024);
  wt_cvt_t<<<256, 256, 0, stream>>>(W_v, Wv_t, 1024, 1024);
  wt_cvt_t<<<256, 256, 0, stream>>>(W_p, Wp_t, 1024, 1024);

  // v-proj (fused f32->bf16 A-staging) + s-proj
  gemm_bf16<0, true><<<512, 256, 0, stream>>>(v_in, Wlv_t, b_lv, vproj_bf, nullptr,
                                              nullptr, nullptr, nullptr, 8192, 1024, 2048);
  gemm_bf16<0, true><<<512, 256, 0, stream>>>(s_in, Wls_t, b_ls, sproj_bf, nullptr,
                                              nullptr, nullptr, nullptr, 8192, 1024, 768);
  // q-proj
  gemm_bf16<2, false><<<512, 256, 0, stream>>>(vproj_bf, Wq_t, b_q, q_bf, nullptr,
                                               nullptr, nullptr, nullptr, 8192, 1024, 1024);
  // vs-proj with fused transpose (writes vs and vs^T)
  gemm_bf16<4, false><<<512, 256, 0, stream>>>(sproj_bf, Wv_t, b_v, vs_bf, nullptr,
                                               vsT_bf, nullptr, nullptr, 8192, 1024, 1024);
  attn_kernel<<<1024, 512, 0, stream>>>(q_bf, vs_bf, vsT_bf, ctx_bf);
  // out-proj + residual(bf16) + pos_v
  gemm_bf16<3, false><<<512, 256, 0, stream>>>(ctx_bf, Wp_t, b_p, nullptr, out,
                                               nullptr, vproj_bf, pos_v, 8192, 1024, 1024);
  ln_kernel<<<8192, 256, 0, stream>>>(out, gamma, beta);
}

// Round 4
// 235.889 us; speedup vs baseline: 1.1963x; 1.0222x over previous
//
#include <hip/hip_runtime.h>

typedef unsigned short u16;
typedef unsigned int   u32;

using bf16x8 = __attribute__((ext_vector_type(8))) short;
using f32x4  = __attribute__((ext_vector_type(4))) float;

#define MFMA16(a, b, c) __builtin_amdgcn_mfma_f32_16x16x32_bf16((a), (b), (c), 0, 0, 0)

__device__ __forceinline__ u16 f2bf(float f) {
  union { float f; u32 u; } x; x.f = f;
  u32 r = x.u + 0x7fffu + ((x.u >> 16) & 1u);
  return (u16)(r >> 16);
}

__device__ __forceinline__ float bf2f(u16 v) {
  union { u32 u; float f; } x; x.u = ((u32)v) << 16;
  return x.f;
}

// packed f32x2 -> bf16x2 (RNE), single instruction; no builtin on gfx950
__device__ __forceinline__ u32 cvtpk(float lo, float hi) {
  u32 r;
  asm("v_cvt_pk_bf16_f32 %0, %1, %2" : "=v"(r) : "v"(lo), "v"(hi));
  return r;
}

// async global->LDS, 16B per lane; LDS dest must be wave-uniform base (HW adds lane*16)
__device__ __forceinline__ void gl2lds16(const void* g, void* l) {
  __builtin_amdgcn_global_load_lds(
      (const __attribute__((address_space(1))) u32*)g,
      (__attribute__((address_space(3))) u32*)l, 16, 0, 0);
}

// ---------------- fp32 -> bf16 elementwise (8 elems/thread) ----------------
__global__ __launch_bounds__(256) void cvt_f32_bf16(const float* __restrict__ in,
                                                    u16* __restrict__ out, long n8) {
  long i = (long)blockIdx.x * 256 + threadIdx.x;
  if (i >= n8) return;
  const float4* p = (const float4*)(in + i * 8);
  float4 a = p[0], b = p[1];
  uint4 pk;
  pk.x = cvtpk(a.x, a.y);
  pk.y = cvtpk(a.z, a.w);
  pk.z = cvtpk(b.x, b.y);
  pk.w = cvtpk(b.z, b.w);
  *(uint4*)(out + i * 8) = pk;
}

// ---------------- weight convert + transpose: W[K][N] f32 -> Wt[N][K] bf16 --
__global__ __launch_bounds__(256) void wt_cvt_t(const float* __restrict__ W,
                                                u16* __restrict__ Wt, int K, int N) {
  __shared__ u16 t[64][66];
  int tilesN = N >> 6;
  int k0 = ((int)blockIdx.x / tilesN) << 6;
  int n0 = ((int)blockIdx.x % tilesN) << 6;
  int tid = threadIdx.x;
  int c4 = (tid & 15) * 4, r16 = tid >> 4;
#pragma unroll
  for (int p = 0; p < 4; ++p) {
    int row = r16 + p * 16;
    float4 f = *(const float4*)(W + (size_t)(k0 + row) * N + n0 + c4);
    t[row][c4 + 0] = f2bf(f.x);
    t[row][c4 + 1] = f2bf(f.y);
    t[row][c4 + 2] = f2bf(f.z);
    t[row][c4 + 3] = f2bf(f.w);
  }
  __syncthreads();
  int c8 = (tid & 7) * 8, r32 = tid >> 3;
#pragma unroll
  for (int p = 0; p < 2; ++p) {
    int n = r32 + p * 32;
    u16 tmp[8] __attribute__((aligned(16)));
#pragma unroll
    for (int e = 0; e < 8; ++e) tmp[e] = t[c8 + e][n];
    *(uint4*)(Wt + (size_t)(n0 + n) * K + k0 + c8) = *(uint4*)tmp;
  }
}

// ---------------- MFMA GEMM: C[M][N] = A[M][K] * Bt[N][K]^T + bias ---------
// 128x128 tile, BK=64, 4 waves (2x2), 64x64 per wave, XOR-swizzled LDS,
// pure global_load_lds staging (fire-and-forget), XCD M-chunked block swizzle.
// MODE 0: relu, write bf16
// MODE 2: write bf16 permuted to [B][H][L][64] (q-proj)
// MODE 4: like 2, plus transposed write [BH][64][512] (vs-proj, fused transpose)
// MODE 3: out = acc + bias + bf2f(add0b[m][n]) + add1[m&511][n], f32 (out-proj)
template <int MODE>
__global__ __launch_bounds__(256) void gemm_bf16(
    const u16* __restrict__ A, const u16* __restrict__ Bt,
    const float* __restrict__ bias, u16* __restrict__ outb, float* __restrict__ outf,
    u16* __restrict__ outt, const u16* __restrict__ add0b,
    const float* __restrict__ add1, int M, int N, int K) {
  __shared__ u16 sA[128 * 64];
  __shared__ u16 sB[128 * 64];
  int tilesN = N >> 7;
  // bijective XCD-chunked swizzle: XCD x owns a contiguous tm range (A stays L2-hot)
  int nwg = (int)gridDim.x;
  int cpx = nwg >> 3;
  int orig = (int)blockIdx.x;
  int wg = (orig & 7) * cpx + (orig >> 3);
  int tm = wg / tilesN, tn = wg % tilesN;
  int m0 = tm << 7, n0 = tn << 7;
  int tid = threadIdx.x, w = tid >> 6, l = tid & 63;
  int wm = (w >> 1) << 6, wn = (w & 1) << 6;
  int c16 = l & 15, g16 = (l >> 4) * 16;

  f32x4 acc[4][4];
#pragma unroll
  for (int i = 0; i < 4; ++i)
#pragma unroll
    for (int j = 0; j < 4; ++j) acc[i][j] = (f32x4){0.f, 0.f, 0.f, 0.f};

  int nk = K >> 6;
  for (int kt = 0; kt < nk; ++kt) {
    __syncthreads();
    const u16* Ab = A + (size_t)m0 * K + kt * 64;
    const u16* Bb = Bt + (size_t)n0 * K + kt * 64;
#pragma unroll
    for (int j = 0; j < 4; ++j) {
      int chunk = w * 4 + j;
      int lin = chunk * 1024 + l * 16;
      int row = lin >> 7;
      int cb = (lin & 127) ^ ((row & 7) << 4);
      gl2lds16(Ab + (size_t)row * K + (cb >> 1), (char*)sA + chunk * 1024);
      gl2lds16(Bb + (size_t)row * K + (cb >> 1), (char*)sB + chunk * 1024);
    }
    __syncthreads();
#pragma unroll
    for (int kk = 0; kk < 2; ++kk) {
      bf16x8 af[4], bfr[4];
#pragma unroll
      for (int i = 0; i < 4; ++i) {
        int ar = wm + i * 16 + c16;
        af[i] = *(const bf16x8*)((const char*)sA + ar * 128 +
                                 ((kk * 64 + g16) ^ ((ar & 7) << 4)));
        int br = wn + i * 16 + c16;
        bfr[i] = *(const bf16x8*)((const char*)sB + br * 128 +
                                  ((kk * 64 + g16) ^ ((br & 7) << 4)));
      }
#pragma unroll
      for (int i = 0; i < 4; ++i)
#pragma unroll
        for (int j = 0; j < 4; ++j) acc[i][j] = MFMA16(af[i], bfr[j], acc[i][j]);
    }
  }
#pragma unroll
  for (int i = 0; i < 4; ++i) {
#pragma unroll
    for (int j = 0; j < 4; ++j) {
      float vv[4];
      int gn = n0 + wn + j * 16 + c16;
#pragma unroll
      for (int r = 0; r < 4; ++r) vv[r] = acc[i][j][r] + bias[gn];
      int gm0 = m0 + wm + i * 16 + (l >> 4) * 4;
      if (MODE == 0) {
#pragma unroll
        for (int r = 0; r < 4; ++r)
          outb[(size_t)(gm0 + r) * N + gn] = f2bf(fmaxf(vv[r], 0.f));
      } else if (MODE == 2 || MODE == 4) {
        int hh = gn >> 6, dk = gn & 63, bb2 = gm0 >> 9, ll2 = gm0 & 511;
#pragma unroll
        for (int r = 0; r < 4; ++r)
          outb[(((size_t)bb2 * 16 + hh) * 512 + ll2 + r) * 64 + dk] = f2bf(vv[r]);
        if (MODE == 4) {
          uint2 tw;
          tw.x = cvtpk(vv[0], vv[1]);
          tw.y = cvtpk(vv[2], vv[3]);
          *(uint2*)(outt + (((size_t)bb2 * 16 + hh) * 64 + dk) * 512 + ll2) = tw;
        }
      } else {  // MODE 3
#pragma unroll
        for (int r = 0; r < 4; ++r) {
          int gm = gm0 + r;
          float v = vv[r] + bf2f(add0b[(size_t)gm * N + gn]) +
                    add1[(size_t)(gm & 511) * N + gn];
          outf[(size_t)gm * N + gn] = v;
        }
      }
    }
  }
}

// ---------------- fused attention: swapped-QK^T + swapped-PV ---------------
__global__ __launch_bounds__(512) void attn_kernel(const u16* __restrict__ q,
                                                   const u16* __restrict__ kv,
                                                   const u16* __restrict__ kvT,
                                                   u16* __restrict__ ctx) {
  __shared__ u16 sK[2][4096];   // [64 keys][64 dk], 128B rows, XOR swizzle
  __shared__ u16 sVT[2][4096];  // [64 dv][64 keys]
  __shared__ u16 sP[8192];      // Q staging (128x64), then per-wave P (16x64 each)

  int orig = (int)blockIdx.x;
  int r = (orig & 7) * 128 + (orig >> 3);
  int bh = r >> 2, qt = r & 3;
  int b = bh >> 4, h = bh & 15;
  int tid = threadIdx.x, w = tid >> 6, l = tid & 63;
  int c16 = l & 15, hi = l >> 4, g16 = hi * 16;
  int swzq = (c16 & 7) << 4;

  const u16* qbase = q + (size_t)bh * 32768 + (size_t)qt * 8192;
#pragma unroll
  for (int j = 0; j < 2; ++j) {
    int chunk = w * 2 + j;
    int lin = chunk * 1024 + l * 16;
    int row = lin >> 7;
    int cb = (lin & 127) ^ ((row & 7) << 4);
    gl2lds16(qbase + (size_t)row * 64 + (cb >> 1), (char*)sP + chunk * 1024);
  }
  {
    const u16* kb = kv + (size_t)bh * 32768;
    const u16* vb = kvT + (size_t)bh * 32768;
    int lin = w * 1024 + l * 16;
    int row = lin >> 7;
    int cb = (lin & 127) ^ ((row & 7) << 4);
    gl2lds16(kb + (size_t)row * 64 + (cb >> 1), (char*)sK[0] + w * 1024);
    gl2lds16(vb + (size_t)row * 512 + (cb >> 1), (char*)sVT[0] + w * 1024);
  }
  __syncthreads();

  const char* sQrow = (const char*)sP + (w * 16 + c16) * 128;
  bf16x8 qf0 = *(const bf16x8*)(sQrow + ((0 + g16) ^ swzq));
  bf16x8 qf1 = *(const bf16x8*)(sQrow + ((64 + g16) ^ swzq));

  char* sPw = (char*)sP + w * 2048;
  f32x4 of[4];
#pragma unroll
  for (int n = 0; n < 4; ++n) of[n] = (f32x4){0.f, 0.f, 0.f, 0.f};
  float m_run = -1e30f, l_run = 0.f;

  for (int c = 0; c < 8; ++c) {
    int cur = c & 1;
    if (c < 7) {
      const u16* kb = kv + (size_t)bh * 32768 + (size_t)(c + 1) * 4096;
      const u16* vb = kvT + (size_t)bh * 32768 + (c + 1) * 64;
      int lin = w * 1024 + l * 16;
      int row = lin >> 7;
      int cb = (lin & 127) ^ ((row & 7) << 4);
      gl2lds16(kb + (size_t)row * 64 + (cb >> 1), (char*)sK[cur ^ 1] + w * 1024);
      gl2lds16(vb + (size_t)row * 512 + (cb >> 1), (char*)sVT[cur ^ 1] + w * 1024);
    }
    const char* kbuf = (const char*)sK[cur];
    const char* vtbuf = (const char*)sVT[cur];

    f32x4 sf[4];
#pragma unroll
    for (int n = 0; n < 4; ++n) {
      const char* krow = kbuf + (n * 16 + c16) * 128;
      bf16x8 k0 = *(const bf16x8*)(krow + (g16 ^ swzq));
      bf16x8 k1 = *(const bf16x8*)(krow + ((64 + g16) ^ swzq));
      f32x4 z = (f32x4){0.f, 0.f, 0.f, 0.f};
      z = MFMA16(k0, qf0, z);
      z = MFMA16(k1, qf1, z);
      sf[n] = z;
    }

    float pmax = -1e30f;
#pragma unroll
    for (int n = 0; n < 4; ++n)
#pragma unroll
      for (int rr = 0; rr < 4; ++rr) {
        sf[n][rr] *= 0.125f;
        pmax = fmaxf(pmax, sf[n][rr]);
      }
    pmax = fmaxf(pmax, __shfl_xor(pmax, 16));
    pmax = fmaxf(pmax, __shfl_xor(pmax, 32));
    float mnew = fmaxf(m_run, pmax);
    float corr = __expf(m_run - mnew);
    float psum = 0.f;
#pragma unroll
    for (int n = 0; n < 4; ++n)
#pragma unroll
      for (int rr = 0; rr < 4; ++rr) {
        float p = __expf(sf[n][rr] - mnew);
        sf[n][rr] = p;
        psum += p;
      }
    psum += __shfl_xor(psum, 16);
    psum += __shfl_xor(psum, 32);
    l_run = l_run * corr + psum;
    m_run = mnew;
#pragma unroll
    for (int n = 0; n < 4; ++n)
#pragma unroll
      for (int rr = 0; rr < 4; ++rr) of[n][rr] *= corr;

#pragma unroll
    for (int n = 0; n < 4; ++n) {
      uint2 pw;
      pw.x = cvtpk(sf[n][0], sf[n][1]);
      pw.y = cvtpk(sf[n][2], sf[n][3]);
      *(uint2*)(sPw + c16 * 128 + ((n * 32 + hi * 8) ^ swzq)) = pw;
    }

    bf16x8 pf0 = *(const bf16x8*)(sPw + c16 * 128 + (g16 ^ swzq));
    bf16x8 pf1 = *(const bf16x8*)(sPw + c16 * 128 + ((64 + g16) ^ swzq));
#pragma unroll
    for (int n = 0; n < 4; ++n) {
      const char* vrow = vtbuf + (n * 16 + c16) * 128;
      bf16x8 v0 = *(const bf16x8*)(vrow + (g16 ^ swzq));
      bf16x8 v1 = *(const bf16x8*)(vrow + ((64 + g16) ^ swzq));
      of[n] = MFMA16(v0, pf0, of[n]);
      of[n] = MFMA16(v1, pf1, of[n]);
    }
    __syncthreads();
  }

  float inv = 1.0f / l_run;
  int grow = qt * 128 + w * 16 + c16;
  u16* obase = ctx + (size_t)(b * 512 + grow) * 1024 + h * 64;
#pragma unroll
  for (int n = 0; n < 4; ++n) {
    uint2 ow;
    ow.x = cvtpk(of[n][0] * inv, of[n][1] * inv);
    ow.y = cvtpk(of[n][2] * inv, of[n][3] * inv);
    *(uint2*)(obase + n * 16 + hi * 4) = ow;
  }
}

// ---------------- in-place LayerNorm over D=1024 ---------------------------
__global__ __launch_bounds__(256) void ln_kernel(float* __restrict__ x,
                                                 const float* __restrict__ gamma,
                                                 const float* __restrict__ beta) {
  __shared__ float red[4];
  __shared__ float red2[4];
  int row = blockIdx.x, tid = threadIdx.x;
  float4 v = *(float4*)(x + (size_t)row * 1024 + tid * 4);
  float s = v.x + v.y + v.z + v.w;
#pragma unroll
  for (int d = 1; d < 64; d <<= 1) s += __shfl_xor(s, d);
  if ((tid & 63) == 0) red[tid >> 6] = s;
  __syncthreads();
  float mu = (red[0] + red[1] + red[2] + red[3]) * (1.0f / 1024.0f);
  float d0 = v.x - mu, d1 = v.y - mu, d2 = v.z - mu, d3 = v.w - mu;
  float qq = d0 * d0 + d1 * d1 + d2 * d2 + d3 * d3;
#pragma unroll
  for (int d = 1; d < 64; d <<= 1) qq += __shfl_xor(qq, d);
  if ((tid & 63) == 0) red2[tid >> 6] = qq;
  __syncthreads();
  float var = (red2[0] + red2[1] + red2[2] + red2[3]) * (1.0f / 1024.0f);
  float rstd = rsqrtf(var + 1e-6f);
  float4 g = *(const float4*)(gamma + tid * 4);
  float4 bb = *(const float4*)(beta + tid * 4);
  v.x = g.x * d0 * rstd + bb.x;
  v.y = g.y * d1 * rstd + bb.y;
  v.z = g.z * d2 * rstd + bb.z;
  v.w = g.w * d3 * rstd + bb.w;
  *(float4*)(x + (size_t)row * 1024 + tid * 4) = v;
}

extern "C" void kernel_launch(void* const* d_in, const int* in_sizes, int n_in,
                              void* d_out, int out_size, void* d_ws, size_t ws_size,
                              hipStream_t stream) {
  (void)in_sizes; (void)n_in; (void)out_size; (void)ws_size;
  const float* v_in  = (const float*)d_in[0];
  const float* s_in  = (const float*)d_in[1];
  const float* W_lv  = (const float*)d_in[2];
  const float* b_lv  = (const float*)d_in[3];
  const float* W_ls  = (const float*)d_in[4];
  const float* b_ls  = (const float*)d_in[5];
  const float* pos_v = (const float*)d_in[6];
  // d_in[7] = pos_s (unused), d_in[10]/[11] = W_k/b_k (discarded in ref)
  const float* W_q   = (const float*)d_in[8];
  const float* b_q   = (const float*)d_in[9];
  const float* W_v   = (const float*)d_in[12];
  const float* b_v   = (const float*)d_in[13];
  const float* W_p   = (const float*)d_in[14];
  const float* b_p   = (const float*)d_in[15];
  const float* gamma = (const float*)d_in[16];
  const float* beta  = (const float*)d_in[17];
  float* out = (float*)d_out;

  char* ws = (char*)d_ws;
  size_t off = 0;
  auto alloc = [&](size_t bytes) {
    char* p = ws + off;
    off += (bytes + 255) & ~(size_t)255;
    return p;
  };
  u16* v_bf     = (u16*)alloc(33554432);   // [8192][2048] bf16
  u16* s_bf     = (u16*)alloc(12582912);   // [8192][768]
  u16* Wlv_t    = (u16*)alloc(4194304);    // [1024][2048] bf16
  u16* Wls_t    = (u16*)alloc(1572864);    // [1024][768]
  u16* Wq_t     = (u16*)alloc(2097152);    // [1024][1024]
  u16* Wv_t     = (u16*)alloc(2097152);
  u16* Wp_t     = (u16*)alloc(2097152);
  u16* vproj_bf = (u16*)alloc(16777216);   // [8192][1024] (also the residual, bf16)
  u16* sproj_bf = (u16*)alloc(16777216);
  u16* q_bf     = (u16*)alloc(16777216);   // [BH][512][64]
  u16* vs_bf    = (u16*)alloc(16777216);   // [BH][512][64]
  u16* vsT_bf   = (u16*)alloc(16777216);   // [BH][64][512]
  u16* ctx_bf   = (u16*)alloc(16777216);   // [8192][1024]

  cvt_f32_bf16<<<8192, 256, 0, stream>>>(v_in, v_bf, 2097152);
  cvt_f32_bf16<<<3072, 256, 0, stream>>>(s_in, s_bf, 786432);
  wt_cvt_t<<<512, 256, 0, stream>>>(W_lv, Wlv_t, 2048, 1024);
  wt_cvt_t<<<192, 256, 0, stream>>>(W_ls, Wls_t, 768, 1024);
  wt_cvt_t<<<256, 256, 0, stream>>>(W_q, Wq_t, 1024, 1024);
  wt_cvt_t<<<256, 256, 0, stream>>>(W_v, Wv_t, 1024, 1024);
  wt_cvt_t<<<256, 256, 0, stream>>>(W_p, Wp_t, 1024, 1024);

  // v-proj + s-proj (bf16 A via gl2lds, fire-and-forget staging)
  gemm_bf16<0><<<512, 256, 0, stream>>>(v_bf, Wlv_t, b_lv, vproj_bf, nullptr,
                                        nullptr, nullptr, nullptr, 8192, 1024, 2048);
  gemm_bf16<0><<<512, 256, 0, stream>>>(s_bf, Wls_t, b_ls, sproj_bf, nullptr,
                                        nullptr, nullptr, nullptr, 8192, 1024, 768);
  // q-proj
  gemm_bf16<2><<<512, 256, 0, stream>>>(vproj_bf, Wq_t, b_q, q_bf, nullptr,
                                        nullptr, nullptr, nullptr, 8192, 1024, 1024);
  // vs-proj with fused transpose (writes vs and vs^T)
  gemm_bf16<4><<<512, 256, 0, stream>>>(sproj_bf, Wv_t, b_v, vs_bf, nullptr,
                                        vsT_bf, nullptr, nullptr, 8192, 1024, 1024);
  attn_kernel<<<1024, 512, 0, stream>>>(q_bf, vs_bf, vsT_bf, ctx_bf);
  // out-proj + residual(bf16) + pos_v
  gemm_bf16<3><<<512, 256, 0, stream>>>(ctx_bf, Wp_t, b_p, nullptr, out,
                                        nullptr, vproj_bf, pos_v, 8192, 1024, 1024);
  ln_kernel<<<8192, 256, 0, stream>>>(out, gamma, beta);
}